// Round 10
// baseline (455.349 us; speedup 1.0000x reference)
//
#include <hip/hip_runtime.h>
#include <stdint.h>

// ---------------- problem constants (from reference) ----------------
#define DIN   4096
#define DOUT  4096
#define RANK  16
#define MTOT  8192            // 4 * 2048
#define LSCALE 2.0f           // alpha/rank = 32/16

typedef unsigned short u16;
typedef __bf16 bf16x8 __attribute__((ext_vector_type(8)));
typedef float  f32x4  __attribute__((ext_vector_type(4)));
typedef u16    u16x8  __attribute__((ext_vector_type(8)));

__device__ __forceinline__ u16 f2bf(float f) {
    uint32_t u = __builtin_bit_cast(uint32_t, f);
    u = (u + 0x7FFFu + ((u >> 16) & 1u)) >> 16;   // RNE
    return (u16)u;
}

__device__ __forceinline__ u16x8 pack8(f32x4 a, f32x4 b) {
    u16x8 o;
    o[0] = f2bf(a[0]); o[1] = f2bf(a[1]); o[2] = f2bf(a[2]); o[3] = f2bf(a[3]);
    o[4] = f2bf(b[0]); o[5] = f2bf(b[1]); o[6] = f2bf(b[2]); o[7] = f2bf(b[3]);
    return o;
}

#define GLDS16(g, l) __builtin_amdgcn_global_load_lds( \
    (const __attribute__((address_space(1))) void*)(g), \
    (__attribute__((address_space(3))) void*)(l), 16, 0, 0)

// ---------------- pass 1a: x (f32) -> xb (bf16) ----------------
__global__ __launch_bounds__(256) void k_convert_x(const float* __restrict__ x,
                                                   u16* __restrict__ xb) {
    long i = ((long)blockIdx.x * 256 + threadIdx.x) * 8;
    f32x4 a = *(const f32x4*)(x + i);
    f32x4 b = *(const f32x4*)(x + i + 4);
    *(u16x8*)(xb + i) = pack8(a, b);
}

// ---------------- pass 1b: W_eff = W + scale * B @ A  (bf16) ----------------
__global__ __launch_bounds__(256) void k_build_weff(const float* __restrict__ W,
                                                    const float* __restrict__ A,
                                                    const float* __restrict__ B,
                                                    u16* __restrict__ wb) {
    long t = (long)blockIdx.x * 256 + threadIdx.x;
    long i = t * 8;
    int o = (int)(i >> 12);        // / DIN
    int d = (int)(i & (DIN - 1));
    float sB[RANK];
#pragma unroll
    for (int r = 0; r < RANK; ++r) sB[r] = B[o * RANK + r] * LSCALE;
    f32x4 w0 = *(const f32x4*)(W + i);
    f32x4 w1 = *(const f32x4*)(W + i + 4);
#pragma unroll
    for (int r = 0; r < RANK; ++r) {
        f32x4 a0 = *(const f32x4*)(A + (long)r * DIN + d);
        f32x4 a1 = *(const f32x4*)(A + (long)r * DIN + d + 4);
        w0 += a0 * sB[r];
        w1 += a1 * sB[r];
    }
    *(u16x8*)(wb + i) = pack8(w0, w1);
}

// ---------------- main GEMM: out = xb @ wb^T + bias ----------------
// FLATMM-style: A via LDS (double-buffered, gload_lds, swizzled), B STREAMED
// global->registers per wave (no LDS, no barriers for B; compiler's counted
// vmcnt hides latency). 256x256 block, BK=64, 8 waves (2Mx4N, wave 128x64).
// LDS traffic/tile: 128 ds_read_b128 + A-writes (~1790cy) < MFMA (2483cy)
// -> LDS off critical path. ONE barrier + ONE vmcnt(12) gate per K-tile.
// Per tile t: issue B(t+1)->other reg set (8x dwordx4); stage A(t+1)->other
// LDS buf (4x gload_lds); GATE vmcnt(12) [retires B(t)+A(t), keeps t+1 in
// flight]; read afL(8), MFMA 32; read afH(8), MFMA 32; ABAR [protects A buf
// overwrite 2 tiles later]. B dbuf via static even/odd reg sets (rule 20).
#define BM 256
#define BN 256
#define BK 64
#define NT (DIN / BK)          // 64 K-tiles

#define MFMA16(d, a, b) d = __builtin_amdgcn_mfma_f32_16x16x32_bf16(a, b, d, 0, 0, 0)
#define ABAR()   asm volatile("s_barrier" ::: "memory")
#define GATE12() asm volatile("s_waitcnt vmcnt(12)" ::: "memory")
#define PRIO1()  __builtin_amdgcn_s_setprio(1)
#define PRIO0()  __builtin_amdgcn_s_setprio(0)

// 32 MFMAs: acc[mo+m][n] += AF[m] x BF[n], kk-outer (16 indep accs between reuses)
#define QUADB(mo, AF, BF) \
    _Pragma("unroll") \
    for (int kk = 0; kk < 2; ++kk) { \
        _Pragma("unroll") \
        for (int m = 0; m < 4; ++m) { \
            _Pragma("unroll") \
            for (int n = 0; n < 4; ++n) { \
                MFMA16(acc[(mo)+m][n], AF[m][kk], BF[n][kk]); \
            } \
        } \
    }

// 8 global B loads into DST[4][2] for K-tile kt
#define LOADB(DST, kt) \
    _Pragma("unroll") \
    for (int nf = 0; nf < 4; ++nf) { \
        _Pragma("unroll") \
        for (int kk = 0; kk < 2; ++kk) { \
            DST[nf][kk] = *(const bf16x8*)(bRow + (long)nf*16*K + (kt)*BK + kk*32); \
        } \
    }

__global__ __launch_bounds__(512, 2) void k_gemm_ws(const u16* __restrict__ xb,
                                                    const u16* __restrict__ wb,
                                                    const float* __restrict__ bias,
                                                    float* __restrict__ out) {
    constexpr int K = DIN, N = DOUT;
    __shared__ alignas(16) u16 lds[32768];   // A only: buf0@0, buf1@16384 (u16)

    // T1: bijective XCD swizzle (gridDim.x = 512, divisible by 8).
    // bm-major within an XCD chunk -> the 32 same-bn blocks are consecutive.
    const int nchunk = gridDim.x >> 3;
    const int bid = blockIdx.x;
    const int wg  = (bid & 7) * nchunk + (bid >> 3);
    const int bm  = (wg & 31) * BM;
    const int bn  = (wg >> 5) * BN;

    const int tid  = threadIdx.x;
    const int lane = tid & 63;
    const int wid  = tid >> 6;         // 0..7
    const int wr   = wid >> 2;         // 0..1 -> rows wr*128..+127
    const int wc   = wid & 3;          // 0..3 -> cols wc*64..+63
    const int lrow = lane & 15;
    const int kgrp = lane >> 4;        // 0..3

    // ---- A staging geometry (pre-swizzled global source, linear LDS dest) ----
    const int srow = tid >> 3;                       // 0..63
    const int sgl  = (tid & 7) ^ (srow & 7);
    const u16* const aSrcB = xb + (long)(bm + srow) * K + sgl * 8;

    // chunk c = tile rows 64c..64c+63 (c = 0..3)
#define STAGE_A(c, buf, kt) GLDS16(aSrcB + (long)(64*(c))*K + (kt)*BK, \
                                   lds + (buf)*16384 + (c)*4096 + tid*8)

    // ---- A fragment-read geometry (swizzled) ----
    const int go0 = (kgrp ^ (lrow & 7)) * 8;   // kk=0 granule (u16 units)
    const int go1 = go0 ^ 32;                  // kk=1 (granule ^ 4)
    const int arow = (wr*128 + lrow) * 64;     // wave A base row offset

    // ---- B streaming base: lane owns output col bn + wc*64 + nf*16 + lrow ----
    const u16* const bRow = wb + (long)(bn + wc*64 + lrow) * K + kgrp * 8;

    f32x4 acc[8][4];
#pragma unroll
    for (int m = 0; m < 8; ++m)
#pragma unroll
        for (int n = 0; n < 4; ++n) acc[m][n] = (f32x4){0.f, 0.f, 0.f, 0.f};

    bf16x8 afL[4][2], afH[4][2], bE[4][2], bO[4][2];

    // ---- prologue: A(0)->buf0, B(0)->bE, full drain ----
    STAGE_A(0, 0, 0); STAGE_A(1, 0, 0);
    STAGE_A(2, 0, 0); STAGE_A(3, 0, 0);
    LOADB(bE, 0);
    asm volatile("s_waitcnt vmcnt(0)" ::: "memory");
    __syncthreads();

    for (int it = 0; it < NT/2; ++it) {
        const int t   = 2*it;
        const int kt1 = t + 1;                 // <= 63
        const int kt2 = (t + 2) & (NT - 1);    // wraps on last iter (unused)

        // ======== even tile t: A in buf0, B = bE; prefetch into buf1/bO ========
        LOADB(bO, kt1);
        STAGE_A(0, 1, kt1); STAGE_A(1, 1, kt1);
        STAGE_A(2, 1, kt1); STAGE_A(3, 1, kt1);
        GATE12();                              // retires B(t)+A(t); keeps t+1
#pragma unroll
        for (int mf = 0; mf < 4; ++mf) {
            const u16* b = lds + arow + mf * 1024;
            afL[mf][0] = *(const bf16x8*)(b + go0);
            afL[mf][1] = *(const bf16x8*)(b + go1);
        }
        PRIO1(); QUADB(0, afL, bE); PRIO0();
#pragma unroll
        for (int mf = 0; mf < 4; ++mf) {
            const u16* b = lds + arow + (mf + 4) * 1024;
            afH[mf][0] = *(const bf16x8*)(b + go0);
            afH[mf][1] = *(const bf16x8*)(b + go1);
        }
        PRIO1(); QUADB(4, afH, bE); PRIO0();
        ABAR();                                // buf0 reads done -> safe to
                                               // restage buf0 next tile
        // ======== odd tile t+1: A in buf1, B = bO; prefetch into buf0/bE ========
        LOADB(bE, kt2);
        STAGE_A(0, 0, kt2); STAGE_A(1, 0, kt2);
        STAGE_A(2, 0, kt2); STAGE_A(3, 0, kt2);
        GATE12();                              // retires B(t+1)+A(t+1)
#pragma unroll
        for (int mf = 0; mf < 4; ++mf) {
            const u16* b = lds + 16384 + arow + mf * 1024;
            afL[mf][0] = *(const bf16x8*)(b + go0);
            afL[mf][1] = *(const bf16x8*)(b + go1);
        }
        PRIO1(); QUADB(0, afL, bO); PRIO0();
#pragma unroll
        for (int mf = 0; mf < 4; ++mf) {
            const u16* b = lds + 16384 + arow + (mf + 4) * 1024;
            afH[mf][0] = *(const bf16x8*)(b + go0);
            afH[mf][1] = *(const bf16x8*)(b + go1);
        }
        PRIO1(); QUADB(4, afH, bO); PRIO0();
        ABAR();
    }
    asm volatile("s_waitcnt vmcnt(0)" ::: "memory");   // drain wrapped prefetch

    // ---- epilogue: + bias, store f32 ----
    const int orow = bm + wr*128 + kgrp*4;
    const int ocol = bn + wc*64 + lrow;
#pragma unroll
    for (int n = 0; n < 4; ++n) {
        const int col = ocol + n*16;
        const float bj = bias[col];
#pragma unroll
        for (int m = 0; m < 8; ++m) {
            const int row = orow + m*16;
#pragma unroll
            for (int r = 0; r < 4; ++r)
                out[(long)(row + r) * N + col] = acc[m][n][r] + bj;
        }
    }
}

// ---------------- fallback: T = scale * x @ A^T  (one wave per row) ----------------
__global__ __launch_bounds__(64) void k_lora_T(const float* __restrict__ x,
                                               const float* __restrict__ A,
                                               float* __restrict__ T) {
    const int m = blockIdx.x;
    const int lane = threadIdx.x;
    const float* xr = x + (long)m * DIN;
    float acc[RANK];
#pragma unroll
    for (int r = 0; r < RANK; ++r) acc[r] = 0.f;
    for (int k = lane * 4; k < DIN; k += 64 * 4) {
        f32x4 xv = *(const f32x4*)(xr + k);
#pragma unroll
        for (int r = 0; r < RANK; ++r) {
            f32x4 av = *(const f32x4*)(A + (long)r * DIN + k);
            acc[r] += xv[0] * av[0] + xv[1] * av[1] + xv[2] * av[2] + xv[3] * av[3];
        }
    }
#pragma unroll
    for (int r = 0; r < RANK; ++r)
        for (int off = 32; off > 0; off >>= 1) acc[r] += __shfl_down(acc[r], off);
    if (lane == 0) {
#pragma unroll
        for (int r = 0; r < RANK; ++r) T[(long)m * RANK + r] = acc[r] * LSCALE;
    }
}

// ---------------- fallback GEMM: f32 sources, reg-staged conversion ----------------
__global__ __launch_bounds__(256) void k_gemm_nows(const float* __restrict__ x,
                                                   const float* __restrict__ W,
                                                   const float* __restrict__ bias,
                                                   const float* __restrict__ T,
                                                   const float* __restrict__ lB,
                                                   float* __restrict__ out) {
    constexpr int FBM = 128, FBN = 128, FBK = 32, K = DIN, N = DOUT;
    __shared__ __align__(16) u16 As[FBM * FBK];
    __shared__ __align__(16) u16 Bs[FBN * FBK];

    const int tid = threadIdx.x;
    const int bm = blockIdx.y * FBM;
    const int bn = blockIdx.x * FBN;
    const int lane = tid & 63;
    const int wid  = tid >> 6;
    const int wr = wid >> 1, wc = wid & 1;
    const int lrow = lane & 15;
    const int kgrp = lane >> 4;

    const int c0 = tid, c1 = tid + 256;
    const float* aS0 = x + (long)(bm + (c0 >> 2)) * K + (c0 & 3) * 8;
    const float* aS1 = x + (long)(bm + (c1 >> 2)) * K + (c1 & 3) * 8;
    const float* bS0 = W + (long)(bn + (c0 >> 2)) * K + (c0 & 3) * 8;
    const float* bS1 = W + (long)(bn + (c1 >> 2)) * K + (c1 & 3) * 8;
    u16* aD0 = As + c0 * 8;  u16* aD1 = As + c1 * 8;
    u16* bD0 = Bs + c0 * 8;  u16* bD1 = Bs + c1 * 8;

    const u16* aR = As + (wr * 64 + lrow) * FBK + kgrp * 8;
    const u16* bR = Bs + (wc * 64 + lrow) * FBK + kgrp * 8;

    f32x4 acc[4][4];
#pragma unroll
    for (int i = 0; i < 4; ++i)
#pragma unroll
        for (int j = 0; j < 4; ++j) acc[i][j] = (f32x4){0.f, 0.f, 0.f, 0.f};

    for (int k0 = 0; k0 < K; k0 += FBK) {
        f32x4 a00 = *(const f32x4*)aS0, a01 = *(const f32x4*)(aS0 + 4);
        f32x4 a10 = *(const f32x4*)aS1, a11 = *(const f32x4*)(aS1 + 4);
        f32x4 b00 = *(const f32x4*)bS0, b01 = *(const f32x4*)(bS0 + 4);
        f32x4 b10 = *(const f32x4*)bS1, b11 = *(const f32x4*)(bS1 + 4);
        aS0 += FBK; aS1 += FBK; bS0 += FBK; bS1 += FBK;
        if (k0) __syncthreads();
        *(u16x8*)aD0 = pack8(a00, a01);
        *(u16x8*)aD1 = pack8(a10, a11);
        *(u16x8*)bD0 = pack8(b00, b01);
        *(u16x8*)bD1 = pack8(b10, b11);
        __syncthreads();

        bf16x8 af[4], bf[4];
#pragma unroll
        for (int i = 0; i < 4; ++i) af[i] = *(const bf16x8*)(aR + i * 16 * FBK);
#pragma unroll
        for (int j = 0; j < 4; ++j) bf[j] = *(const bf16x8*)(bR + j * 16 * FBK);
#pragma unroll
        for (int i = 0; i < 4; ++i)
#pragma unroll
            for (int j = 0; j < 4; ++j)
                acc[i][j] = __builtin_amdgcn_mfma_f32_16x16x32_bf16(af[i], bf[j], acc[i][j], 0, 0, 0);
    }

#pragma unroll
    for (int j = 0; j < 4; ++j) {
        const int col = bn + wc * 64 + j * 16 + lrow;
        const float bj = bias[col];
        float bl[RANK];
#pragma unroll
        for (int q = 0; q < RANK; ++q) bl[q] = lB[(long)col * RANK + q];
#pragma unroll
        for (int i = 0; i < 4; ++i) {
            const int row0 = bm + wr * 64 + i * 16 + kgrp * 4;
#pragma unroll
            for (int r = 0; r < 4; ++r) {
                const int row = row0 + r;
                const float* Trow = T + (long)row * RANK;
                float s = bj;
#pragma unroll
                for (int q = 0; q < RANK; ++q) s += Trow[q] * bl[q];
                out[(long)row * N + col] = acc[i][j][r] + s;
            }
        }
    }
}

extern "C" void kernel_launch(void* const* d_in, const int* in_sizes, int n_in,
                              void* d_out, int out_size, void* d_ws, size_t ws_size,
                              hipStream_t stream) {
    const float* x    = (const float*)d_in[0];
    const float* W    = (const float*)d_in[1];
    const float* bias = (const float*)d_in[2];
    const float* lA   = (const float*)d_in[3];
    const float* lB   = (const float*)d_in[4];
    float* out = (float*)d_out;

    const size_t xb_bytes = (size_t)MTOT * DIN * sizeof(u16);   // 64 MiB
    const size_t wb_bytes = (size_t)DOUT * DIN * sizeof(u16);   // 32 MiB

    if (ws_size >= xb_bytes + wb_bytes) {
        u16* xb = (u16*)d_ws;
        u16* wb = (u16*)((char*)d_ws + xb_bytes);
        k_convert_x <<<(int)((long)MTOT * DIN / 8 / 256), 256, 0, stream>>>(x, xb);
        k_build_weff<<<(int)((long)DOUT * DIN / 8 / 256), 256, 0, stream>>>(W, lA, lB, wb);
        k_gemm_ws   <<<(MTOT / BM) * (DOUT / BN), 512, 0, stream>>>(xb, wb, bias, out);
    } else {
        float* T = (float*)d_ws;   // 512 KiB
        k_lora_T   <<<MTOT, 64, 0, stream>>>(x, lA, T);
        k_gemm_nows<<<dim3(DOUT / 128, MTOT / 128), 256, 0, stream>>>(x, W, bias, T, lB, out);
    }
}

// Round 11
// 345.259 us; speedup vs baseline: 1.3189x; 1.3189x over previous
//
#include <hip/hip_runtime.h>
#include <stdint.h>

// ---------------- problem constants (from reference) ----------------
#define DIN   4096
#define DOUT  4096
#define RANK  16
#define MTOT  8192            // 4 * 2048
#define LSCALE 2.0f           // alpha/rank = 32/16

typedef unsigned short u16;
typedef __bf16 bf16x8 __attribute__((ext_vector_type(8)));
typedef float  f32x4  __attribute__((ext_vector_type(4)));
typedef float  f32x16 __attribute__((ext_vector_type(16)));
typedef u16    u16x8  __attribute__((ext_vector_type(8)));

__device__ __forceinline__ u16 f2bf(float f) {
    uint32_t u = __builtin_bit_cast(uint32_t, f);
    u = (u + 0x7FFFu + ((u >> 16) & 1u)) >> 16;   // RNE
    return (u16)u;
}

__device__ __forceinline__ u16x8 pack8(f32x4 a, f32x4 b) {
    u16x8 o;
    o[0] = f2bf(a[0]); o[1] = f2bf(a[1]); o[2] = f2bf(a[2]); o[3] = f2bf(a[3]);
    o[4] = f2bf(b[0]); o[5] = f2bf(b[1]); o[6] = f2bf(b[2]); o[7] = f2bf(b[3]);
    return o;
}

#define GLDS16(g, l) __builtin_amdgcn_global_load_lds( \
    (const __attribute__((address_space(1))) void*)(g), \
    (__attribute__((address_space(3))) void*)(l), 16, 0, 0)

// ---------------- pass 1a: x (f32) -> xb (bf16) ----------------
__global__ __launch_bounds__(256) void k_convert_x(const float* __restrict__ x,
                                                   u16* __restrict__ xb) {
    long i = ((long)blockIdx.x * 256 + threadIdx.x) * 8;
    f32x4 a = *(const f32x4*)(x + i);
    f32x4 b = *(const f32x4*)(x + i + 4);
    *(u16x8*)(xb + i) = pack8(a, b);
}

// ---------------- pass 1b: W_eff = W + scale * B @ A  (bf16) ----------------
__global__ __launch_bounds__(256) void k_build_weff(const float* __restrict__ W,
                                                    const float* __restrict__ A,
                                                    const float* __restrict__ B,
                                                    u16* __restrict__ wb) {
    long t = (long)blockIdx.x * 256 + threadIdx.x;
    long i = t * 8;
    int o = (int)(i >> 12);        // / DIN
    int d = (int)(i & (DIN - 1));
    float sB[RANK];
#pragma unroll
    for (int r = 0; r < RANK; ++r) sB[r] = B[o * RANK + r] * LSCALE;
    f32x4 w0 = *(const f32x4*)(W + i);
    f32x4 w1 = *(const f32x4*)(W + i + 4);
#pragma unroll
    for (int r = 0; r < RANK; ++r) {
        f32x4 a0 = *(const f32x4*)(A + (long)r * DIN + d);
        f32x4 a1 = *(const f32x4*)(A + (long)r * DIN + d + 4);
        w0 += a0 * sB[r];
        w1 += a1 * sB[r];
    }
    *(u16x8*)(wb + i) = pack8(w0, w1);
}

// ---------------- main GEMM: out = xb @ wb^T + bias ----------------
// Round-9 schedule + 32x32x16 MFMA (m119: 2495 TF ceiling, -17% matrix-pipe
// floor, half the instruction count). 256x256, BK=64, 8 waves (2Mx4N, wave
// 128x64 = 4x2 accs of f32x16). Per K-tile 4 phases = 4 k-steps of K=16:
//   P_k: read 4 A-frags(ks); stage; MFMA 8 (all independent accs); BAR
// All B-frags of tile t+1 (8x b128) read ONCE post-gate at P4(t) into the
// other static reg set (bE/bO) -> B LDS regions never read in-phase ->
// overwrite-safe with >=2 barriers. Stages: P1 A.lo(t+1), P2 A.hi(t+1),
// P3 B.lo(t+2), P4 B.hi(t+2)+GATE vmcnt(4) (retires A(t+1)+B(t+1); keeps
// B(t+2) in flight; never 0 in loop).
#define BM 256
#define BN 256
#define BK 64
#define NT (DIN / BK)          // 64 K-tiles

#define MFMA32(d, a, b) d = __builtin_amdgcn_mfma_f32_32x32x16_bf16(a, b, d, 0, 0, 0)
#define ABAR()   asm volatile("s_barrier" ::: "memory")
#define GATE4()  asm volatile("s_waitcnt vmcnt(4)" ::: "memory")
#define PRIO1()  __builtin_amdgcn_s_setprio(1)
#define PRIO0()  __builtin_amdgcn_s_setprio(0)

// read the 4 A-frags of one k-step (G = swizzled granule byte-off/2)
#define READ_AKS(AF, ABASE, G) \
    _Pragma("unroll") \
    for (int mi = 0; mi < 4; ++mi) \
        AF[mi] = *(const bf16x8*)((ABASE) + mi * 2048 + (G));

// 8 independent MFMAs of one k-step
#define MFMA8(AF, BR, ks) \
    _Pragma("unroll") \
    for (int mi = 0; mi < 4; ++mi) { \
        MFMA32(acc[mi][0], AF[mi], BR[0][ks]); \
        MFMA32(acc[mi][1], AF[mi], BR[1][ks]); \
    }

// read all 8 B-frags of a tile (2 ni x 4 ks)
#define READ_B8(BR, BBASE) \
    _Pragma("unroll") \
    for (int ni = 0; ni < 2; ++ni) { \
        BR[ni][0] = *(const bf16x8*)((BBASE) + ni * 2048 + g0s); \
        BR[ni][1] = *(const bf16x8*)((BBASE) + ni * 2048 + g1s); \
        BR[ni][2] = *(const bf16x8*)((BBASE) + ni * 2048 + g2s); \
        BR[ni][3] = *(const bf16x8*)((BBASE) + ni * 2048 + g3s); \
    }

__global__ __launch_bounds__(512, 2) void k_gemm_ws(const u16* __restrict__ xb,
                                                    const u16* __restrict__ wb,
                                                    const float* __restrict__ bias,
                                                    float* __restrict__ out) {
    constexpr int K = DIN, N = DOUT;
    __shared__ alignas(16) u16 lds[65536];   // A0@0 A1@16384 B0@32768 B1@49152 (u16)

    // T1: bijective XCD swizzle (gridDim.x = 512, divisible by 8)
    const int nchunk = gridDim.x >> 3;
    const int bid = blockIdx.x;
    const int wg  = (bid & 7) * nchunk + (bid >> 3);
    const int bm  = (wg & 31) * BM;
    const int bn  = (wg >> 5) * BN;

    const int tid  = threadIdx.x;
    const int lane = tid & 63;
    const int wid  = tid >> 6;         // 0..7
    const int wr   = wid >> 2;         // 0..1 -> rows wr*128..+127
    const int wc   = wid & 3;          // 0..3 -> cols wc*64..+63
    const int l31  = lane & 31;
    const int h    = lane >> 5;        // 0..1 (k-half)
    const int lsw  = lane & 7;

    // ---- staging geometry (pre-swizzled global source, linear LDS dest) ----
    const int srow = tid >> 3;                       // 0..63
    const int sgl  = (tid & 7) ^ (srow & 7);
    const u16* const aSrcB = xb + (long)(bm + srow) * K + sgl * 8;
    const u16* const bSrcB = wb + (long)(bn + srow) * K + sgl * 8;

    // chunk c = tile rows 64c..64c+63. lo = c0,c1; hi = c2,c3.
#define STAGE_A(c, buf, kt) GLDS16(aSrcB + (long)(64*(c))*K + (kt)*BK, \
                                   lds + (buf)*16384 + (c)*4096 + tid*8)
#define STAGE_B(c, buf, kt) GLDS16(bSrcB + (long)(64*(c))*K + (kt)*BK, \
                                   lds + 32768 + (buf)*16384 + (c)*4096 + tid*8)

    // ---- fragment-read geometry (swizzled), 32x32x16 layout:
    // operand row = lane&31, k = ks*16 + (lane>>5)*8 + j  (contiguous 8)
    const int g0s = ((0 + h) ^ lsw) * 8;       // ks=0 granule (u16 units)
    const int g1s = ((2 + h) ^ lsw) * 8;
    const int g2s = ((4 + h) ^ lsw) * 8;
    const int g3s = ((6 + h) ^ lsw) * 8;
    const int arowB = (wr*128 + l31) * 64;     // wave A base row offset (u16)
    const int bcolB = (wc*64  + l31) * 64;     // wave B base row offset (u16)

    const u16* const cA0 = lds +         arowB;
    const u16* const cA1 = lds + 16384 + arowB;
    const u16* const cB0 = lds + 32768 +         bcolB;
    const u16* const cB1 = lds + 32768 + 16384 + bcolB;

    f32x16 acc[4][2];
#pragma unroll
    for (int mi = 0; mi < 4; ++mi)
#pragma unroll
        for (int ni = 0; ni < 2; ++ni)
#pragma unroll
            for (int r = 0; r < 16; ++r) acc[mi][ni][r] = 0.f;

    bf16x8 af[4], bE[2][4], bO[2][4];

    // ---- prologue: A(0)->buf0, B(0)->buf0, B(1)->buf1; drain; B(0)->bE ----
    STAGE_A(0, 0, 0); STAGE_A(1, 0, 0);
    STAGE_A(2, 0, 0); STAGE_A(3, 0, 0);
    STAGE_B(0, 0, 0); STAGE_B(1, 0, 0);
    STAGE_B(2, 0, 0); STAGE_B(3, 0, 0);
    STAGE_B(0, 1, 1); STAGE_B(1, 1, 1);
    STAGE_B(2, 1, 1); STAGE_B(3, 1, 1);
    asm volatile("s_waitcnt vmcnt(0)" ::: "memory");
    __syncthreads();
    READ_B8(bE, cB0);

    for (int it = 0; it < NT/2; ++it) {
        const int kt1 = 2*it + 1;              // <= 63
        const int kt2 = (2*it + 2) & (NT - 1); // wraps (unused data on last)
        const int kt3 = (2*it + 3) & (NT - 1);

        // ============ even tile t (A buf0, B regs bE) ============
        READ_AKS(af, cA0, g0s);
        STAGE_A(0, 1, kt1); STAGE_A(1, 1, kt1);
        PRIO1(); MFMA8(af, bE, 0); PRIO0();
        ABAR();

        READ_AKS(af, cA0, g1s);
        STAGE_A(2, 1, kt1); STAGE_A(3, 1, kt1);
        PRIO1(); MFMA8(af, bE, 1); PRIO0();
        ABAR();

        READ_AKS(af, cA0, g2s);
        STAGE_B(0, 0, kt2); STAGE_B(1, 0, kt2);
        PRIO1(); MFMA8(af, bE, 2); PRIO0();
        ABAR();

        STAGE_B(2, 0, kt2); STAGE_B(3, 0, kt2);
        GATE4();                               // retires A(t+1)+B(t+1)
        READ_AKS(af, cA0, g3s);
        READ_B8(bO, cB1);                      // B(t+1) -> regs
        PRIO1(); MFMA8(af, bE, 3); PRIO0();
        ABAR();

        // ============ odd tile t+1 (A buf1, B regs bO) ============
        READ_AKS(af, cA1, g0s);
        STAGE_A(0, 0, kt2); STAGE_A(1, 0, kt2);
        PRIO1(); MFMA8(af, bO, 0); PRIO0();
        ABAR();

        READ_AKS(af, cA1, g1s);
        STAGE_A(2, 0, kt2); STAGE_A(3, 0, kt2);
        PRIO1(); MFMA8(af, bO, 1); PRIO0();
        ABAR();

        READ_AKS(af, cA1, g2s);
        STAGE_B(0, 1, kt3); STAGE_B(1, 1, kt3);
        PRIO1(); MFMA8(af, bO, 2); PRIO0();
        ABAR();

        STAGE_B(2, 1, kt3); STAGE_B(3, 1, kt3);
        GATE4();                               // retires A(t+2)+B(t+2)
        READ_AKS(af, cA1, g3s);
        READ_B8(bE, cB0);                      // B(t+2) -> regs
        PRIO1(); MFMA8(af, bO, 3); PRIO0();
        ABAR();
    }
    asm volatile("s_waitcnt vmcnt(0)" ::: "memory");   // drain wrapped prefetch

    // ---- epilogue: + bias, store f32 (32x32 C/D: col=lane&31,
    //      row=(r&3)+8*(r>>2)+4*(lane>>5)) ----
    const int orow = bm + wr*128;
    const int ocol = bn + wc*64 + l31;
#pragma unroll
    for (int ni = 0; ni < 2; ++ni) {
        const int col = ocol + ni*32;
        const float bj = bias[col];
#pragma unroll
        for (int mi = 0; mi < 4; ++mi) {
#pragma unroll
            for (int r = 0; r < 16; ++r) {
                const int row = orow + mi*32 + (r & 3) + 8*(r >> 2) + 4*h;
                out[(long)row * N + col] = acc[mi][ni][r] + bj;
            }
        }
    }
}

// ---------------- fallback: T = scale * x @ A^T  (one wave per row) ----------------
__global__ __launch_bounds__(64) void k_lora_T(const float* __restrict__ x,
                                               const float* __restrict__ A,
                                               float* __restrict__ T) {
    const int m = blockIdx.x;
    const int lane = threadIdx.x;
    const float* xr = x + (long)m * DIN;
    float acc[RANK];
#pragma unroll
    for (int r = 0; r < RANK; ++r) acc[r] = 0.f;
    for (int k = lane * 4; k < DIN; k += 64 * 4) {
        f32x4 xv = *(const f32x4*)(xr + k);
#pragma unroll
        for (int r = 0; r < RANK; ++r) {
            f32x4 av = *(const f32x4*)(A + (long)r * DIN + k);
            acc[r] += xv[0] * av[0] + xv[1] * av[1] + xv[2] * av[2] + xv[3] * av[3];
        }
    }
#pragma unroll
    for (int r = 0; r < RANK; ++r)
        for (int off = 32; off > 0; off >>= 1) acc[r] += __shfl_down(acc[r], off);
    if (lane == 0) {
#pragma unroll
        for (int r = 0; r < RANK; ++r) T[(long)m * RANK + r] = acc[r] * LSCALE;
    }
}

// ---------------- fallback GEMM: f32 sources, reg-staged conversion ----------------
__global__ __launch_bounds__(256) void k_gemm_nows(const float* __restrict__ x,
                                                   const float* __restrict__ W,
                                                   const float* __restrict__ bias,
                                                   const float* __restrict__ T,
                                                   const float* __restrict__ lB,
                                                   float* __restrict__ out) {
    constexpr int FBM = 128, FBN = 128, FBK = 32, K = DIN, N = DOUT;
    __shared__ __align__(16) u16 As[FBM * FBK];
    __shared__ __align__(16) u16 Bs[FBN * FBK];

    const int tid = threadIdx.x;
    const int bm = blockIdx.y * FBM;
    const int bn = blockIdx.x * FBN;
    const int lane = tid & 63;
    const int wid  = tid >> 6;
    const int wr = wid >> 1, wc = wid & 1;
    const int lrow = lane & 15;
    const int kgrp = lane >> 4;

    const int c0 = tid, c1 = tid + 256;
    const float* aS0 = x + (long)(bm + (c0 >> 2)) * K + (c0 & 3) * 8;
    const float* aS1 = x + (long)(bm + (c1 >> 2)) * K + (c1 & 3) * 8;
    const float* bS0 = W + (long)(bn + (c0 >> 2)) * K + (c0 & 3) * 8;
    const float* bS1 = W + (long)(bn + (c1 >> 2)) * K + (c1 & 3) * 8;
    u16* aD0 = As + c0 * 8;  u16* aD1 = As + c1 * 8;
    u16* bD0 = Bs + c0 * 8;  u16* bD1 = Bs + c1 * 8;

    const u16* aR = As + (wr * 64 + lrow) * FBK + kgrp * 8;
    const u16* bR = Bs + (wc * 64 + lrow) * FBK + kgrp * 8;

    f32x4 acc[4][4];
#pragma unroll
    for (int i = 0; i < 4; ++i)
#pragma unroll
        for (int j = 0; j < 4; ++j) acc[i][j] = (f32x4){0.f, 0.f, 0.f, 0.f};

    for (int k0 = 0; k0 < K; k0 += FBK) {
        f32x4 a00 = *(const f32x4*)aS0, a01 = *(const f32x4*)(aS0 + 4);
        f32x4 a10 = *(const f32x4*)aS1, a11 = *(const f32x4*)(aS1 + 4);
        f32x4 b00 = *(const f32x4*)bS0, b01 = *(const f32x4*)(bS0 + 4);
        f32x4 b10 = *(const f32x4*)bS1, b11 = *(const f32x4*)(bS1 + 4);
        aS0 += FBK; aS1 += FBK; bS0 += FBK; bS1 += FBK;
        if (k0) __syncthreads();
        *(u16x8*)aD0 = pack8(a00, a01);
        *(u16x8*)aD1 = pack8(a10, a11);
        *(u16x8*)bD0 = pack8(b00, b01);
        *(u16x8*)bD1 = pack8(b10, b11);
        __syncthreads();

        bf16x8 af[4], bf[4];
#pragma unroll
        for (int i = 0; i < 4; ++i) af[i] = *(const bf16x8*)(aR + i * 16 * FBK);
#pragma unroll
        for (int j = 0; j < 4; ++j) bf[j] = *(const bf16x8*)(bR + j * 16 * FBK);
#pragma unroll
        for (int i = 0; i < 4; ++i)
#pragma unroll
            for (int j = 0; j < 4; ++j)
                acc[i][j] = __builtin_amdgcn_mfma_f32_16x16x32_bf16(af[i], bf[j], acc[i][j], 0, 0, 0);
    }

#pragma unroll
    for (int j = 0; j < 4; ++j) {
        const int col = bn + wc * 64 + j * 16 + lrow;
        const float bj = bias[col];
        float bl[RANK];
#pragma unroll
        for (int q = 0; q < RANK; ++q) bl[q] = lB[(long)col * RANK + q];
#pragma unroll
        for (int i = 0; i < 4; ++i) {
            const int row0 = bm + wr * 64 + i * 16 + kgrp * 4;
#pragma unroll
            for (int r = 0; r < 4; ++r) {
                const int row = row0 + r;
                const float* Trow = T + (long)row * RANK;
                float s = bj;
#pragma unroll
                for (int q = 0; q < RANK; ++q) s += Trow[q] * bl[q];
                out[(long)row * N + col] = acc[i][j][r] + s;
            }
        }
    }
}

extern "C" void kernel_launch(void* const* d_in, const int* in_sizes, int n_in,
                              void* d_out, int out_size, void* d_ws, size_t ws_size,
                              hipStream_t stream) {
    const float* x    = (const float*)d_in[0];
    const float* W    = (const float*)d_in[1];
    const float* bias = (const float*)d_in[2];
    const float* lA   = (const float*)d_in[3];
    const float* lB   = (const float*)d_in[4];
    float* out = (float*)d_out;

    const size_t xb_bytes = (size_t)MTOT * DIN * sizeof(u16);   // 64 MiB
    const size_t wb_bytes = (size_t)DOUT * DIN * sizeof(u16);   // 32 MiB

    if (ws_size >= xb_bytes + wb_bytes) {
        u16* xb = (u16*)d_ws;
        u16* wb = (u16*)((char*)d_ws + xb_bytes);
        k_convert_x <<<(int)((long)MTOT * DIN / 8 / 256), 256, 0, stream>>>(x, xb);
        k_build_weff<<<(int)((long)DOUT * DIN / 8 / 256), 256, 0, stream>>>(W, lA, lB, wb);
        k_gemm_ws   <<<(MTOT / BM) * (DOUT / BN), 512, 0, stream>>>(xb, wb, bias, out);
    } else {
        float* T = (float*)d_ws;   // 512 KiB
        k_lora_T   <<<MTOT, 64, 0, stream>>>(x, lA, T);
        k_gemm_nows<<<dim3(DOUT / 128, MTOT / 128), 256, 0, stream>>>(x, W, bias, T, lB, out);
    }
}

// Round 12
// 289.617 us; speedup vs baseline: 1.5722x; 1.1921x over previous
//
#include <hip/hip_runtime.h>
#include <stdint.h>

// ---------------- problem constants (from reference) ----------------
#define DIN   4096
#define DOUT  4096
#define RANK  16
#define MTOT  8192            // 4 * 2048
#define LSCALE 2.0f           // alpha/rank = 32/16

typedef unsigned short u16;
typedef __bf16 bf16x8 __attribute__((ext_vector_type(8)));
typedef float  f32x4  __attribute__((ext_vector_type(4)));
typedef u16    u16x8  __attribute__((ext_vector_type(8)));

__device__ __forceinline__ u16 f2bf(float f) {
    uint32_t u = __builtin_bit_cast(uint32_t, f);
    u = (u + 0x7FFFu + ((u >> 16) & 1u)) >> 16;   // RNE
    return (u16)u;
}

__device__ __forceinline__ u16x8 pack8(f32x4 a, f32x4 b) {
    u16x8 o;
    o[0] = f2bf(a[0]); o[1] = f2bf(a[1]); o[2] = f2bf(a[2]); o[3] = f2bf(a[3]);
    o[4] = f2bf(b[0]); o[5] = f2bf(b[1]); o[6] = f2bf(b[2]); o[7] = f2bf(b[3]);
    return o;
}

#define GLDS16(g, l) __builtin_amdgcn_global_load_lds( \
    (const __attribute__((address_space(1))) void*)(g), \
    (__attribute__((address_space(3))) void*)(l), 16, 0, 0)

// ---------------- pass 1a: x (f32) -> xb (bf16) ----------------
__global__ __launch_bounds__(256) void k_convert_x(const float* __restrict__ x,
                                                   u16* __restrict__ xb) {
    long i = ((long)blockIdx.x * 256 + threadIdx.x) * 8;
    f32x4 a = *(const f32x4*)(x + i);
    f32x4 b = *(const f32x4*)(x + i + 4);
    *(u16x8*)(xb + i) = pack8(a, b);
}

// ---------------- pass 1b: W_eff = W + scale * B @ A  (bf16) ----------------
// Thread owns one d-chunk (8 f32) and 16 consecutive o rows; the 16 A-chunks
// are hoisted to registers once and reused 16x (A L2 traffic 1GB -> 64MB).
#define WEFF_OPG 16
__global__ __launch_bounds__(256) void k_build_weff(const float* __restrict__ W,
                                                    const float* __restrict__ A,
                                                    const float* __restrict__ B,
                                                    u16* __restrict__ wb) {
    const long t = (long)blockIdx.x * 256 + threadIdx.x;   // 512 dchunks x 256 ogroups
    const int dc = (int)(t & 511);
    const int og = (int)(t >> 9);
    const int d  = dc * 8;
    f32x4 a0[RANK], a1[RANK];
#pragma unroll
    for (int r = 0; r < RANK; ++r) {
        a0[r] = *(const f32x4*)(A + (long)r * DIN + d);
        a1[r] = *(const f32x4*)(A + (long)r * DIN + d + 4);
    }
#pragma unroll 4
    for (int j = 0; j < WEFF_OPG; ++j) {
        const int o = og * WEFF_OPG + j;
        const long i = (long)o * DIN + d;
        f32x4 w0 = *(const f32x4*)(W + i);
        f32x4 w1 = *(const f32x4*)(W + i + 4);
#pragma unroll
        for (int r = 0; r < RANK; ++r) {
            const float s = B[o * RANK + r] * LSCALE;
            w0 += a0[r] * s;
            w1 += a1[r] * s;
        }
        *(u16x8*)(wb + i) = pack8(w0, w1);
    }
}

// ---------------- main GEMM: out = xb @ wb^T + bias ----------------
// 256x256, BK=64, 8 waves (2Mx4N, wave 128x64), 16x16x32 MFMA, TWO phases
// (two barriers) per K-tile:
//   Ph1: stage A.lo+A.hi(t+1)->nxt; read afL(8)+bfHi(4); Q1=afL*bfLo,
//        Q2=afL*bfHi; BAR
//   Ph2: stage B.lo+B.hi(t+2)->cur; GATE vmcnt(4); read afH(8)+bfLo(t+1)(4);
//        Q3=afH*bfLo, Q4=afH*bfHi; BAR
// FIFO at Ph2 gate: outstanding = B(t+1)[4] + A(t+1)[4] + B(t+2)[4] = 12;
// vmcnt(4) retires B(t+1)+A(t+1) (read next phase), keeps B(t+2) in flight.
// Write-after-read: every stage target's last reads were consumed (lgkm)
// before the previous barrier -> 1-barrier gap suffices. vmcnt never 0.
#define BM 256
#define BN 256
#define BK 64
#define NT (DIN / BK)          // 64 K-tiles

#define MFMA16(d, a, b) d = __builtin_amdgcn_mfma_f32_16x16x32_bf16(a, b, d, 0, 0, 0)
#define ABAR()   asm volatile("s_barrier" ::: "memory")
#define GATE4()  asm volatile("s_waitcnt vmcnt(4)" ::: "memory")
#define PRIO1()  __builtin_amdgcn_s_setprio(1)
#define PRIO0()  __builtin_amdgcn_s_setprio(0)

// 16 MFMAs, kk-outer (8 independent accs between dependent reuses)
#define QUADK(mo, no, AF, BF) \
    _Pragma("unroll") \
    for (int kk = 0; kk < 2; ++kk) { \
        _Pragma("unroll") \
        for (int m = 0; m < 4; ++m) { \
            _Pragma("unroll") \
            for (int n = 0; n < 2; ++n) { \
                MFMA16(acc[(mo)+m][(no)+n], AF[m][kk], BF[n][kk]); \
            } \
        } \
    }

__global__ __launch_bounds__(512, 2) void k_gemm_ws(const u16* __restrict__ xb,
                                                    const u16* __restrict__ wb,
                                                    const float* __restrict__ bias,
                                                    float* __restrict__ out) {
    constexpr int K = DIN, N = DOUT;
    __shared__ alignas(16) u16 lds[65536];   // A0@0 A1@16384 B0@32768 B1@49152 (u16)

    // T1: bijective XCD swizzle (gridDim.x = 512, divisible by 8)
    const int nchunk = gridDim.x >> 3;
    const int bid = blockIdx.x;
    const int wg  = (bid & 7) * nchunk + (bid >> 3);
    const int bm  = (wg & 31) * BM;
    const int bn  = (wg >> 5) * BN;

    const int tid  = threadIdx.x;
    const int lane = tid & 63;
    const int wid  = tid >> 6;         // 0..7
    const int wr   = wid >> 2;         // 0..1 -> rows wr*128..+127
    const int wc   = wid & 3;          // 0..3 -> cols wc*64..+63
    const int lrow = lane & 15;
    const int kgrp = lane >> 4;        // 0..3

    // ---- staging geometry (T2: pre-swizzled global source, linear LDS dest) ----
    const int srow = tid >> 3;                       // 0..63
    const int sgl  = (tid & 7) ^ (srow & 7);
    const u16* const aSrcB = xb + (long)(bm + srow) * K + sgl * 8;
    const u16* const bSrcB = wb + (long)(bn + srow) * K + sgl * 8;

    // chunk c = tile rows 64c..64c+63. lo = c0,c1; hi = c2,c3.
#define STAGE_A(c, buf, kt) GLDS16(aSrcB + (long)(64*(c))*K + (kt)*BK, \
                                   lds + (buf)*16384 + (c)*4096 + tid*8)
#define STAGE_B(c, buf, kt) GLDS16(bSrcB + (long)(64*(c))*K + (kt)*BK, \
                                   lds + 32768 + (buf)*16384 + (c)*4096 + tid*8)

    // ---- fragment-read geometry (swizzled) ----
    const int go0 = (kgrp ^ (lrow & 7)) * 8;   // kk=0 granule (u16 units)
    const int go1 = go0 ^ 32;                  // kk=1 (granule ^ 4)
    const int arow = (wr*128 + lrow) * 64;     // wave A base row offset
    const int brow = (wc*64  + lrow) * 64;     // wave B base row offset

    const u16* const cA0 = lds +         arow;
    const u16* const cA1 = lds + 16384 + arow;
    const u16* const cB0 = lds + 32768 +         brow;
    const u16* const cB1 = lds + 32768 + 16384 + brow;

    f32x4 acc[8][4];
#pragma unroll
    for (int m = 0; m < 8; ++m)
#pragma unroll
        for (int n = 0; n < 4; ++n) acc[m][n] = (f32x4){0.f, 0.f, 0.f, 0.f};

    bf16x8 afL[4][2], afH[4][2], bfHi[2][2], bLoA[2][2], bLoB[2][2];

#define READ_AF(DST, BASE, OFS) \
    _Pragma("unroll") \
    for (int mf = 0; mf < 4; ++mf) { \
        const u16* b_ = (BASE) + ((OFS) + mf) * 1024; \
        DST[mf][0] = *(const bf16x8*)(b_ + go0); \
        DST[mf][1] = *(const bf16x8*)(b_ + go1); \
    }
#define READ_BF(DST, BASE, OFS) \
    _Pragma("unroll") \
    for (int nf = 0; nf < 2; ++nf) { \
        const u16* b_ = (BASE) + ((OFS) + nf) * 1024; \
        DST[nf][0] = *(const bf16x8*)(b_ + go0); \
        DST[nf][1] = *(const bf16x8*)(b_ + go1); \
    }

    // ---- prologue: A(0),B(0)->buf0; B(1)->buf1; counted gate; read bfLo(0) ----
    STAGE_A(0, 0, 0); STAGE_A(1, 0, 0);
    STAGE_A(2, 0, 0); STAGE_A(3, 0, 0);
    STAGE_B(0, 0, 0); STAGE_B(1, 0, 0);
    STAGE_B(2, 0, 0); STAGE_B(3, 0, 0);
    STAGE_B(0, 1, 1); STAGE_B(1, 1, 1);
    STAGE_B(2, 1, 1); STAGE_B(3, 1, 1);
    GATE4();                       // retires A(0)+B(0); keeps B(1) in flight
    __syncthreads();
    READ_BF(bLoA, cB0, 0);

    for (int it = 0; it < NT/2; ++it) {
        const int kt1 = 2*it + 1;              // <= 63
        const int kt2 = (2*it + 2) & (NT - 1); // wraps on last iter (unused)
        const int kt3 = (2*it + 3) & (NT - 1);

        // ================= even tile t=2it (A buf0, B buf0, bfLo=bLoA) ==========
        // Ph1: stage A(t+1)->buf1; read afL + bfHi; Q1,Q2
        STAGE_A(0, 1, kt1); STAGE_A(1, 1, kt1);
        STAGE_A(2, 1, kt1); STAGE_A(3, 1, kt1);
        READ_AF(afL, cA0, 0);
        READ_BF(bfHi, cB0, 2);
        PRIO1(); QUADK(0, 0, afL, bLoA); QUADK(0, 2, afL, bfHi); PRIO0();
        ABAR();
        // Ph2: stage B(t+2)->buf0; GATE; read afH + bfLo(t+1); Q3,Q4
        STAGE_B(0, 0, kt2); STAGE_B(1, 0, kt2);
        STAGE_B(2, 0, kt2); STAGE_B(3, 0, kt2);
        GATE4();                               // retires A(t+1)+B(t+1)
        READ_AF(afH, cA0, 4);
        READ_BF(bLoB, cB1, 0);
        PRIO1(); QUADK(4, 0, afH, bLoA); QUADK(4, 2, afH, bfHi); PRIO0();
        ABAR();

        // ================= odd tile t+1 (A buf1, B buf1, bfLo=bLoB) =============
        STAGE_A(0, 0, kt2); STAGE_A(1, 0, kt2);
        STAGE_A(2, 0, kt2); STAGE_A(3, 0, kt2);
        READ_AF(afL, cA1, 0);
        READ_BF(bfHi, cB1, 2);
        PRIO1(); QUADK(0, 0, afL, bLoB); QUADK(0, 2, afL, bfHi); PRIO0();
        ABAR();

        STAGE_B(0, 1, kt3); STAGE_B(1, 1, kt3);
        STAGE_B(2, 1, kt3); STAGE_B(3, 1, kt3);
        GATE4();                               // retires A(t+2)+B(t+2)
        READ_AF(afH, cA1, 4);
        READ_BF(bLoA, cB0, 0);
        PRIO1(); QUADK(4, 0, afH, bLoB); QUADK(4, 2, afH, bfHi); PRIO0();
        ABAR();
    }
    asm volatile("s_waitcnt vmcnt(0)" ::: "memory");   // drain wrapped prefetch

    // ---- epilogue: + bias, store f32 ----
    const int orow = bm + wr*128 + kgrp*4;
    const int ocol = bn + wc*64 + lrow;
#pragma unroll
    for (int n = 0; n < 4; ++n) {
        const int col = ocol + n*16;
        const float bj = bias[col];
#pragma unroll
        for (int m = 0; m < 8; ++m) {
            const int row = orow + m*16;
#pragma unroll
            for (int r = 0; r < 4; ++r)
                out[(long)(row + r) * N + col] = acc[m][n][r] + bj;
        }
    }
}

// ---------------- fallback: T = scale * x @ A^T  (one wave per row) ----------------
__global__ __launch_bounds__(64) void k_lora_T(const float* __restrict__ x,
                                               const float* __restrict__ A,
                                               float* __restrict__ T) {
    const int m = blockIdx.x;
    const int lane = threadIdx.x;
    const float* xr = x + (long)m * DIN;
    float acc[RANK];
#pragma unroll
    for (int r = 0; r < RANK; ++r) acc[r] = 0.f;
    for (int k = lane * 4; k < DIN; k += 64 * 4) {
        f32x4 xv = *(const f32x4*)(xr + k);
#pragma unroll
        for (int r = 0; r < RANK; ++r) {
            f32x4 av = *(const f32x4*)(A + (long)r * DIN + k);
            acc[r] += xv[0] * av[0] + xv[1] * av[1] + xv[2] * av[2] + xv[3] * av[3];
        }
    }
#pragma unroll
    for (int r = 0; r < RANK; ++r)
        for (int off = 32; off > 0; off >>= 1) acc[r] += __shfl_down(acc[r], off);
    if (lane == 0) {
#pragma unroll
        for (int r = 0; r < RANK; ++r) T[(long)m * RANK + r] = acc[r] * LSCALE;
    }
}

// ---------------- fallback GEMM: f32 sources, reg-staged conversion ----------------
__global__ __launch_bounds__(256) void k_gemm_nows(const float* __restrict__ x,
                                                   const float* __restrict__ W,
                                                   const float* __restrict__ bias,
                                                   const float* __restrict__ T,
                                                   const float* __restrict__ lB,
                                                   float* __restrict__ out) {
    constexpr int FBM = 128, FBN = 128, FBK = 32, K = DIN, N = DOUT;
    __shared__ __align__(16) u16 As[FBM * FBK];
    __shared__ __align__(16) u16 Bs[FBN * FBK];

    const int tid = threadIdx.x;
    const int bm = blockIdx.y * FBM;
    const int bn = blockIdx.x * FBN;
    const int lane = tid & 63;
    const int wid  = tid >> 6;
    const int wr = wid >> 1, wc = wid & 1;
    const int lrow = lane & 15;
    const int kgrp = lane >> 4;

    const int c0 = tid, c1 = tid + 256;
    const float* aS0 = x + (long)(bm + (c0 >> 2)) * K + (c0 & 3) * 8;
    const float* aS1 = x + (long)(bm + (c1 >> 2)) * K + (c1 & 3) * 8;
    const float* bS0 = W + (long)(bn + (c0 >> 2)) * K + (c0 & 3) * 8;
    const float* bS1 = W + (long)(bn + (c1 >> 2)) * K + (c1 & 3) * 8;
    u16* aD0 = As + c0 * 8;  u16* aD1 = As + c1 * 8;
    u16* bD0 = Bs + c0 * 8;  u16* bD1 = Bs + c1 * 8;

    const u16* aR = As + (wr * 64 + lrow) * FBK + kgrp * 8;
    const u16* bR = Bs + (wc * 64 + lrow) * FBK + kgrp * 8;

    f32x4 acc[4][4];
#pragma unroll
    for (int i = 0; i < 4; ++i)
#pragma unroll
        for (int j = 0; j < 4; ++j) acc[i][j] = (f32x4){0.f, 0.f, 0.f, 0.f};

    for (int k0 = 0; k0 < K; k0 += FBK) {
        f32x4 a00 = *(const f32x4*)aS0, a01 = *(const f32x4*)(aS0 + 4);
        f32x4 a10 = *(const f32x4*)aS1, a11 = *(const f32x4*)(aS1 + 4);
        f32x4 b00 = *(const f32x4*)bS0, b01 = *(const f32x4*)(bS0 + 4);
        f32x4 b10 = *(const f32x4*)bS1, b11 = *(const f32x4*)(bS1 + 4);
        aS0 += FBK; aS1 += FBK; bS0 += FBK; bS1 += FBK;
        if (k0) __syncthreads();
        *(u16x8*)aD0 = pack8(a00, a01);
        *(u16x8*)aD1 = pack8(a10, a11);
        *(u16x8*)bD0 = pack8(b00, b01);
        *(u16x8*)bD1 = pack8(b10, b11);
        __syncthreads();

        bf16x8 af[4], bf[4];
#pragma unroll
        for (int i = 0; i < 4; ++i) af[i] = *(const bf16x8*)(aR + i * 16 * FBK);
#pragma unroll
        for (int j = 0; j < 4; ++j) bf[j] = *(const bf16x8*)(bR + j * 16 * FBK);
#pragma unroll
        for (int i = 0; i < 4; ++i)
#pragma unroll
            for (int j = 0; j < 4; ++j)
                acc[i][j] = __builtin_amdgcn_mfma_f32_16x16x32_bf16(af[i], bf[j], acc[i][j], 0, 0, 0);
    }

#pragma unroll
    for (int j = 0; j < 4; ++j) {
        const int col = bn + wc * 64 + j * 16 + lrow;
        const float bj = bias[col];
        float bl[RANK];
#pragma unroll
        for (int q = 0; q < RANK; ++q) bl[q] = lB[(long)col * RANK + q];
#pragma unroll
        for (int i = 0; i < 4; ++i) {
            const int row0 = bm + wr * 64 + i * 16 + kgrp * 4;
#pragma unroll
            for (int r = 0; r < 4; ++r) {
                const int row = row0 + r;
                const float* Trow = T + (long)row * RANK;
                float s = bj;
#pragma unroll
                for (int q = 0; q < RANK; ++q) s += Trow[q] * bl[q];
                out[(long)row * N + col] = acc[i][j][r] + s;
            }
        }
    }
}

extern "C" void kernel_launch(void* const* d_in, const int* in_sizes, int n_in,
                              void* d_out, int out_size, void* d_ws, size_t ws_size,
                              hipStream_t stream) {
    const float* x    = (const float*)d_in[0];
    const float* W    = (const float*)d_in[1];
    const float* bias = (const float*)d_in[2];
    const float* lA   = (const float*)d_in[3];
    const float* lB   = (const float*)d_in[4];
    float* out = (float*)d_out;

    const size_t xb_bytes = (size_t)MTOT * DIN * sizeof(u16);   // 64 MiB
    const size_t wb_bytes = (size_t)DOUT * DIN * sizeof(u16);   // 32 MiB

    if (ws_size >= xb_bytes + wb_bytes) {
        u16* xb = (u16*)d_ws;
        u16* wb = (u16*)((char*)d_ws + xb_bytes);
        k_convert_x <<<(int)((long)MTOT * DIN / 8 / 256), 256, 0, stream>>>(x, xb);
        k_build_weff<<<(DOUT / WEFF_OPG) * (DIN / 8) / 256, 256, 0, stream>>>(W, lA, lB, wb);
        k_gemm_ws   <<<(MTOT / BM) * (DOUT / BN), 512, 0, stream>>>(xb, wb, bias, out);
    } else {
        float* T = (float*)d_ws;   // 512 KiB
        k_lora_T   <<<MTOT, 64, 0, stream>>>(x, lA, T);
        k_gemm_nows<<<dim3(DOUT / 128, MTOT / 128), 256, 0, stream>>>(x, W, bias, T, lB, out);
    }
}